// Round 1
// baseline (126.297 us; speedup 1.0000x reference)
//
#include <hip/hip_runtime.h>

#define HH 1024
#define WW 1024

// Each thread: one even/odd column pair (x0, x0+1) x 4 consecutive rows.
// Rows alternate parity; green (pass-through) sites are x%2==y%2 (GRBG), so
// each row needs exactly ONE computed pixel at the opposite-parity column.
// Tile row base is a multiple of 4 -> parity of row p is p&1 (compile-time),
// so all window indices are static and the 8x6 window lives in registers.
__global__ __launch_bounds__(256, 2)
void demosaick_kernel(const float* __restrict__ mosaick,
                      const float* __restrict__ sel_filts,
                      const float* __restrict__ green_filts,
                      float* __restrict__ out, int HW) {
    __shared__ float filt[25][16];  // [tap][0..7]=sel, [8..15]=green (64B/tap, b128-friendly)

    const int tid = threadIdx.y * 64 + threadIdx.x;
    for (int idx = tid; idx < 400; idx += 256) {
        int half = idx / 200;            // 0 = sel, 1 = green
        int j = idx - half * 200;        // j = k*25 + tap
        int k = j / 25;
        int t = j - k * 25;
        filt[t][half * 8 + k] = half ? green_filts[j] : sel_filts[j];
    }
    __syncthreads();

    const int b  = blockIdx.z;
    const int y0 = blockIdx.y * 16 + threadIdx.y * 4;       // even
    const int x0 = (blockIdx.x * 64 + threadIdx.x) * 2;     // even
    const float* img = mosaick + (size_t)b * HW;

    // 8 rows x 6 cols window: rows y0-2..y0+5, cols x0-2..x0+3, edge-clamped.
    float win[8][6];
    #pragma unroll
    for (int j = 0; j < 8; ++j) {
        int r = y0 + j - 2;
        r = r < 0 ? 0 : (r > HH - 1 ? HH - 1 : r);
        const float* rp = img + r * WW;
        #pragma unroll
        for (int i = 0; i < 6; ++i) {
            int c = x0 + i - 2;
            c = c < 0 ? 0 : (c > WW - 1 ? WW - 1 : c);
            win[j][i] = rp[c];
        }
    }

    float aS[4][8];   // selection scores, 4 pixels x 8 filters
    float aG[4][8];   // green candidates
    #pragma unroll
    for (int p = 0; p < 4; ++p)
        #pragma unroll
        for (int k = 0; k < 8; ++k) { aS[p][k] = 0.f; aG[p][k] = 0.f; }

    const float4* fl4 = (const float4*)&filt[0][0];
    #pragma unroll
    for (int dy = 0; dy < 5; ++dy) {
        #pragma unroll
        for (int dx = 0; dx < 5; ++dx) {
            const int t = dy * 5 + dx;
            float fS[8], fG[8];
            *(float4*)&fS[0] = fl4[t * 4 + 0];
            *(float4*)&fS[4] = fl4[t * 4 + 1];
            *(float4*)&fG[0] = fl4[t * 4 + 2];
            *(float4*)&fG[4] = fl4[t * 4 + 3];
            #pragma unroll
            for (int p = 0; p < 4; ++p) {
                // p even -> row even -> computed pixel at x0+1 (offset 1)
                // p odd  -> row odd  -> computed pixel at x0   (offset 0)
                float v = win[p + dy][dx + ((p & 1) ^ 1)];
                #pragma unroll
                for (int k = 0; k < 8; ++k) {
                    aS[p][k] = fmaf(v, fS[k], aS[p][k]);
                    aG[p][k] = fmaf(v, fG[k], aG[p][k]);
                }
            }
        }
    }

    float* outp = out + (size_t)b * HW;
    #pragma unroll
    for (int p = 0; p < 4; ++p) {
        float m = aS[p][0];
        #pragma unroll
        for (int k = 1; k < 8; ++k) m = fmaxf(m, aS[p][k]);
        float s = 0.f, gh = 0.f;
        #pragma unroll
        for (int k = 0; k < 8; ++k) {
            float e = __expf(aS[p][k] - m);
            s += e;
            gh = fmaf(e, aG[p][k], gh);
        }
        gh /= s;
        float2 o;
        if ((p & 1) == 0) { o.x = win[p + 2][2]; o.y = gh; }          // green at x0
        else              { o.x = gh;            o.y = win[p + 2][3]; } // green at x0+1
        *(float2*)(outp + (size_t)(y0 + p) * WW + x0) = o;
    }
}

extern "C" void kernel_launch(void* const* d_in, const int* in_sizes, int n_in,
                              void* d_out, int out_size, void* d_ws, size_t ws_size,
                              hipStream_t stream) {
    const float* mosaick     = (const float*)d_in[0];
    const float* sel_filts   = (const float*)d_in[1];
    const float* green_filts = (const float*)d_in[2];
    float* out = (float*)d_out;
    const int HW = HH * WW;
    const int B = in_sizes[0] / HW;          // 8
    dim3 grid(WW / 128, HH / 16, B);         // (8, 64, 8) = 4096 blocks
    dim3 block(64, 4, 1);
    hipLaunchKernelGGL(demosaick_kernel, grid, block, 0, stream,
                       mosaick, sel_filts, green_filts, out, HW);
}